// Round 6
// baseline (210.802 us; speedup 1.0000x reference)
//
#include <hip/hip_runtime.h>
#include <hip/hip_bf16.h>

// Problem constants (from reference)
#define B_   256
#define M_   64
#define T_   1200
#define FT_  10
#define K_   17
#define POOLK_ 75
#define TP_  76            // pooled length
#define NCH_ 240           // 5-output chunks per row
#define NSEG_ 80           // 15-output segments per row
#define FEAT_ (FT_*TP_)    // 760

// Prep: transpose conv weights to k-major -> uniform compile-time offsets -> s_load.
__global__ void prep_weights(const float* __restrict__ conv_w,
                             float* __restrict__ wT) {
    int i = threadIdx.x;
    if (i < FT_*K_) {
        int f = i / K_, k = i - f*K_;
        wT[k*FT_ + f] = conv_w[i];
    }
}

// One filter-group: NF filters starting at F0; 5 conv outputs per thread.
// Window comes straight from GLOBAL memory (L1-hot, 4.8KB row shared by the
// block) -- zero LDS traffic in the hot loop (R1-R5: LDS-issue-bound).
template<int F0, int NF>
__device__ __forceinline__ void conv_group(const float* __restrict__ gx,   // row base
                                           const float* __restrict__ wT,
                                           const float* __restrict__ conv_b,
                                           const int t, const bool edge,
                                           float* __restrict__ C5)
{
    float xw[24];
    if (!edge) {
        // inputs for outputs [5t,5t+5) are x[5t-8 .. 5t+12] (21 floats);
        // load 24 via 6 dwordx4 (dword-aligned; global ops allow it).
        const float* p = gx + 5*t - 8;
        #pragma unroll
        for (int q = 0; q < 6; ++q) {
            float4 v = *(const float4*)(p + 4*q);
            xw[4*q+0] = v.x; xw[4*q+1] = v.y; xw[4*q+2] = v.z; xw[4*q+3] = v.w;
        }
    } else {
        #pragma unroll
        for (int j = 0; j < 21; ++j) {
            const int idx = 5*t - 8 + j;
            xw[j] = (idx >= 0 && idx < T_) ? gx[idx] : 0.f;
        }
        xw[21] = xw[22] = xw[23] = 0.f;
    }
    #pragma unroll
    for (int j = 0; j < 21; ++j) asm volatile("" : "+v"(xw[j]));  // no remat/sink

    float acc[NF][5];
    #pragma unroll
    for (int f = 0; f < NF; ++f) {
        const float bf = conv_b[F0 + f];          // uniform -> SGPR
        #pragma unroll
        for (int p = 0; p < 5; ++p) acc[f][p] = bf;
    }

    #pragma unroll
    for (int k = 0; k < K_; ++k) {
        #pragma unroll
        for (int f = 0; f < NF; ++f) {
            const float w = wT[k*FT_ + F0 + f];   // uniform const offset -> s_load
            acc[f][0] = fmaf(xw[k    ], w, acc[f][0]);
            acc[f][1] = fmaf(xw[k + 1], w, acc[f][1]);
            acc[f][2] = fmaf(xw[k + 2], w, acc[f][2]);
            acc[f][3] = fmaf(xw[k + 3], w, acc[f][3]);
            acc[f][4] = fmaf(xw[k + 4], w, acc[f][4]);
        }
    }

    #pragma unroll
    for (int f = 0; f < NF; ++f) {
        float cs = acc[f][0]*acc[f][0];
        cs = fmaf(acc[f][1], acc[f][1], cs);
        cs = fmaf(acc[f][2], acc[f][2], cs);
        cs = fmaf(acc[f][3], acc[f][3], cs);
        cs = fmaf(acc[f][4], acc[f][4], cs);
        C5[(F0 + f)*NCH_ + t] = cs;
    }
}

__global__ __launch_bounds__(256, 6)
void ChannelScorer_Distributed_39024072851482_kernel(
    const float* __restrict__ x,      // (B,1,M,T) -> (B*M, T)
    const float* __restrict__ wT,     // (K, FT) in d_ws
    const float* __restrict__ conv_b, // (FT,)
    const float* __restrict__ lin_w,  // (M, FEAT)
    const float* __restrict__ lin_b,  // (M,)
    float* __restrict__ out)          // (B,M,1)
{
    __shared__ float C5[FT_ * NCH_];   // 2400: per-(f,chunk) sum of squares
    __shared__ float S15[FT_ * NSEG_]; // 800
    __shared__ float red[4];

    const int row = blockIdx.x;        // b*M_ + m
    const int m   = row & (M_-1);
    const int tid = threadIdx.x;
    const float* gx = x + (size_t)row * T_;

    // ---- phase B: 5 conv outputs/thread, filters in 2 groups of 5 ----
    if (tid < NCH_) {
        // t=237's 6th dwordx4 would read 1 element past the (page-exact)
        // buffer end on the last row -> scalar path for t in {0,1,237,238,239}.
        const bool edge = (tid < 2) | (tid >= 237);
        conv_group<0, 5>(gx, wT, conv_b, tid, edge, C5);
        conv_group<5, 5>(gx, wT, conv_b, tid, edge, C5);
    }
    __syncthreads();

    // ---- phase C: segment sums S15[f][g] = sum of 3 chunk sums ----
    for (int i = tid; i < FT_*NSEG_; i += 256) {
        const int f = i / NSEG_;
        const int g = i - f*NSEG_;
        const float* c = &C5[f*NCH_ + 3*g];
        S15[i] = c[0] + c[1] + c[2];
    }
    __syncthreads();

    // ---- phase D: pooled -> log -> dot with lin_w[m,:] ----
    float partial = 0.f;
    const float* lw = lin_w + m * FEAT_;
    for (int i = tid; i < FEAT_; i += 256) {
        const int f = i / TP_;
        const int p = i - f*TP_;
        const float* s = &S15[f*NSEG_ + p];
        float v = (s[0] + s[1] + s[2] + s[3] + s[4]) * (1.0f/POOLK_);
        v = fmaxf(v, 1e-10f);
        partial = fmaf(__logf(v), lw[i], partial);
    }

    // ---- block reduction ----
    #pragma unroll
    for (int off = 32; off > 0; off >>= 1)
        partial += __shfl_down(partial, off, 64);
    const int wave = tid >> 6, lane = tid & 63;
    if (lane == 0) red[wave] = partial;
    __syncthreads();
    if (tid == 0)
        out[row] = red[0] + red[1] + red[2] + red[3] + lin_b[m];
}

extern "C" void kernel_launch(void* const* d_in, const int* in_sizes, int n_in,
                              void* d_out, int out_size, void* d_ws, size_t ws_size,
                              hipStream_t stream) {
    const float* x      = (const float*)d_in[0];
    const float* conv_w = (const float*)d_in[1];
    const float* conv_b = (const float*)d_in[2];
    const float* lin_w  = (const float*)d_in[3];
    const float* lin_b  = (const float*)d_in[4];
    float* out = (float*)d_out;
    float* wT  = (float*)d_ws;   // 170 floats

    prep_weights<<<1, 192, 0, stream>>>(conv_w, wT);

    dim3 grid(B_ * M_);
    dim3 block(256);
    ChannelScorer_Distributed_39024072851482_kernel<<<grid, block, 0, stream>>>(
        x, wT, conv_b, lin_w, lin_b, out);
}